// Round 5
// baseline (286.195 us; speedup 1.0000x reference)
//
#include <hip/hip_runtime.h>
#include <math.h>

#define INV_TAU 1000.0f
#define TEMP    0.1f
#define CEXP    -1442.6950408889634f   // -1000 * log2(e)

// Problem: B=2,H=8 -> BH=16; N=256; L=64.  X,Y: [BH,256,64] f32. out: [BH,256,256] f32.
//
// Round 5: pipelined K-loop (double-buffered fp16 exp tables, 1 barrier/slab),
// no gamma materialization (pass2 recomputes with w folded, partial-buffer +
// reduce epilogue), shuffle-bitonic sortz with banded Z.
//
// ws (floats): cost[16*65536] | srtu | lziu | srtv | lziv (262144 ea) |
//              swds[1024] | wts[1024] | pws[8*16*65536]

typedef __attribute__((ext_vector_type(8))) _Float16 half8;
typedef __attribute__((ext_vector_type(8))) short short8;
typedef __attribute__((ext_vector_type(4))) float f32x4;

__device__ __forceinline__ float fexp2(float x) { return __builtin_amdgcn_exp2f(x); }

__device__ __forceinline__ half8 ldsh8(const unsigned short* p) {
  return __builtin_bit_cast(half8, *(const short8*)p);
}

// swizzled short-offset of (row, group g of 8 i's) in a 32-short-per-row table
__device__ __forceinline__ int tswz(int row, int g) {
  return row * 32 + (((g + (row >> 1)) & 3) << 3);
}

// K1: cost[bh][j][k] = sqrt(max(|Xj|^2+|Yk|^2-2Xj.Yk, 1e-12))
__global__ __launch_bounds__(256) void cost_kernel(const float* __restrict__ X,
                                                   const float* __restrict__ Y,
                                                   float* __restrict__ cost) {
  const int j = blockIdx.x, bh = blockIdx.y, k = threadIdx.x;
  __shared__ __align__(16) float xr[64];
  if (k < 64) xr[k] = X[((size_t)bh*256 + j)*64 + k];
  __syncthreads();
  const float4* yp = (const float4*)(Y + ((size_t)bh*256 + k)*64);
  const float4* xp = (const float4*)xr;
  float dot = 0.f, x2 = 0.f, y2 = 0.f;
#pragma unroll
  for (int t = 0; t < 16; ++t) {
    float4 yv = yp[t], xv = xp[t];
    dot += xv.x*yv.x + xv.y*yv.y + xv.z*yv.z + xv.w*yv.w;
    x2  += xv.x*xv.x + xv.y*xv.y + xv.z*xv.z + xv.w*xv.w;
    y2  += yv.x*yv.x + yv.y*yv.y + yv.z*yv.z + yv.w*yv.w;
  }
  float c = x2 + y2 - 2.f*dot;
  cost[((size_t)bh*256 + j)*256 + k] = sqrtf(fmaxf(c, 1e-12f));
}

// K2: shuffle-bitonic descending sort + banded Z (1/Z via -log2, row max of logits = 0).
// 1 element/thread; only j in {64,128} cross waves (LDS), j<=32 via shfl_xor.
__global__ __launch_bounds__(256) void sortz_kernel(const float* __restrict__ X,
                                                    const float* __restrict__ Y,
                                                    float* __restrict__ srtu, float* __restrict__ lziu,
                                                    float* __restrict__ srtv, float* __restrict__ lziv) {
  const int l = blockIdx.x, bh = blockIdx.y, tid = threadIdx.x;
  const float* S = blockIdx.z ? Y : X;
  float* so = blockIdx.z ? srtv : srtu;
  float* zo = blockIdx.z ? lziv : lziu;
  __shared__ float s[256];
  float v = S[((size_t)bh*256 + tid)*64 + l];
#pragma unroll
  for (int k = 2; k <= 256; k <<= 1) {
#pragma unroll
    for (int j = k >> 1; j > 0; j >>= 1) {
      float o;
      if (j >= 64) {
        s[tid] = v; __syncthreads();
        o = s[tid ^ j]; __syncthreads();
      } else {
        o = __shfl_xor(v, j, 64);
      }
      const bool up    = ((tid & k) == 0);
      const bool lower = ((tid & j) == 0);
      float mn = fminf(v, o), mx = fmaxf(v, o);
      v = (up == lower) ? mn : mx;
    }
  }
  s[tid] = v; __syncthreads();
  const int jc = 255 - tid;          // rank (descending) -> position in ascending array
  const float sv = s[jc];
  const int lo = jc > 48 ? jc - 48 : 0;
  const int hi = jc < 207 ? jc + 48 : 255;
  float z = 0.f;
  for (int jj = lo; jj <= hi; ++jj) { float d = s[jj] - sv; z += fexp2(d*d*CEXP); }
  const int base = (bh*64 + l)*256 + tid;
  so[base] = sv; zo[base] = -__log2f(z);
}

// ---- staging: one 32-i slab of the fp16 exp tables (swizzled layout) ----
__device__ __forceinline__ void stage_slab(int t, int ib,
                                           const float* __restrict__ su, const float* __restrict__ sv,
                                           const float* __restrict__ srtU, const float* __restrict__ lziU,
                                           const float* __restrict__ srtV, const float* __restrict__ lziV,
                                           unsigned short* __restrict__ EU,
                                           unsigned short* __restrict__ EV) {
  const int r  = t & 127;
  const int gp = (t >> 7) << 1;
  const int i0 = ib + (gp << 3);
  {
    float v = su[r];
    float e[16];
#pragma unroll
    for (int ii = 0; ii < 16; ++ii) {
      float d = v - srtU[i0 + ii];
      e[ii] = fexp2(fmaf(d*d, CEXP, lziU[i0 + ii]));
    }
#pragma unroll
    for (int gg = 0; gg < 2; ++gg) {
      uint4 w;
      w.x = __builtin_bit_cast(unsigned, __builtin_amdgcn_cvt_pkrtz(e[gg*8+0], e[gg*8+1]));
      w.y = __builtin_bit_cast(unsigned, __builtin_amdgcn_cvt_pkrtz(e[gg*8+2], e[gg*8+3]));
      w.z = __builtin_bit_cast(unsigned, __builtin_amdgcn_cvt_pkrtz(e[gg*8+4], e[gg*8+5]));
      w.w = __builtin_bit_cast(unsigned, __builtin_amdgcn_cvt_pkrtz(e[gg*8+6], e[gg*8+7]));
      *(uint4*)&EU[tswz(r, gp + gg)] = w;
    }
  }
#pragma unroll
  for (int rr = 0; rr < 2; ++rr) {
    const int row = r + rr*128;
    float v = sv[row];
    float e[16];
#pragma unroll
    for (int ii = 0; ii < 16; ++ii) {
      float d = v - srtV[i0 + ii];
      e[ii] = fexp2(fmaf(d*d, CEXP, lziV[i0 + ii]));
    }
#pragma unroll
    for (int gg = 0; gg < 2; ++gg) {
      uint4 w;
      w.x = __builtin_bit_cast(unsigned, __builtin_amdgcn_cvt_pkrtz(e[gg*8+0], e[gg*8+1]));
      w.y = __builtin_bit_cast(unsigned, __builtin_amdgcn_cvt_pkrtz(e[gg*8+2], e[gg*8+3]));
      w.z = __builtin_bit_cast(unsigned, __builtin_amdgcn_cvt_pkrtz(e[gg*8+4], e[gg*8+5]));
      w.w = __builtin_bit_cast(unsigned, __builtin_amdgcn_cvt_pkrtz(e[gg*8+6], e[gg*8+7]));
      *(uint4*)&EV[tswz(row, gp + gg)] = w;
    }
  }
}

// pipelined 8-slab strip GEMM body: frag reads of slab s, staging of slab s+1
// into the other buffer, MFMA, one barrier per slab.
__device__ __forceinline__ void strip_body(int tid, int wj, int wk, int inner,
    const float* su, const float* sv,
    const float* srtU, const float* lziU, const float* srtV, const float* lziV,
    unsigned short* EU0, unsigned short* EV0,
    unsigned short* EU1, unsigned short* EV1,
    f32x4 acc[32]) {
  stage_slab(tid, 0, su, sv, srtU, lziU, srtV, lziV, EU0, EV0);
  __syncthreads();
#pragma unroll 1
  for (int s = 0; s < 8; ++s) {
    const unsigned short* EUc = (s & 1) ? EU1 : EU0;
    const unsigned short* EVc = (s & 1) ? EV1 : EV0;
    unsigned short* EUn = (s & 1) ? EU0 : EU1;
    unsigned short* EVn = (s & 1) ? EV0 : EV1;
    half8 B[8], A[4];
#pragma unroll
    for (int nt = 0; nt < 8; ++nt) B[nt] = ldsh8(&EVc[(wk + nt*16)*32 + inner]);
#pragma unroll
    for (int mt = 0; mt < 4; ++mt) A[mt] = ldsh8(&EUc[(wj + mt*16)*32 + inner]);
    if (s < 7)
      stage_slab(tid, (s+1)*32, su, sv, srtU, lziU, srtV, lziV, EUn, EVn);
#pragma unroll
    for (int mt = 0; mt < 4; ++mt)
#pragma unroll
      for (int nt = 0; nt < 8; ++nt)
        acc[mt*8+nt] = __builtin_amdgcn_mfma_f32_16x16x32_f16(A[mt], B[nt], acc[mt*8+nt], 0, 0, 0);
    __syncthreads();
  }
}

// Pass 1: per (strip sb, l, bh): Gamma strip (128j x 256k), dot with cost -> swds.
__global__ __launch_bounds__(256, 2) void pass1_kernel(
    const float* __restrict__ X, const float* __restrict__ Y,
    const float* __restrict__ cost,
    const float* __restrict__ srtu, const float* __restrict__ lziu,
    const float* __restrict__ srtv, const float* __restrict__ lziv,
    float* __restrict__ swds) {
  const int sb = blockIdx.x, l = blockIdx.y, bh = blockIdx.z;
  const int j0 = sb * 128;
  const int tid = threadIdx.x, wave = tid >> 6, lane = tid & 63;
  const int wj = (wave & 1) * 64, wk = (wave >> 1) * 128;
  const int m = lane & 15, q = lane >> 4;
  const int inner = m*32 + (((q + (m >> 1)) & 3) << 3);

  __shared__ float su[128], sv[256];
  __shared__ float srtU[256], lziU[256], srtV[256], lziV[256];
  __shared__ __align__(16) unsigned short EU0[128*32], EU1[128*32];
  __shared__ __align__(16) unsigned short EV0[256*32], EV1[256*32];
  __shared__ float red[4];

  const int lb = (bh*64 + l)*256;
  if (tid < 128) su[tid] = X[((size_t)bh*256 + j0 + tid)*64 + l];
  sv[tid]   = Y[((size_t)bh*256 + tid)*64 + l];
  srtU[tid] = srtu[lb + tid]; lziU[tid] = lziu[lb + tid];
  srtV[tid] = srtv[lb + tid]; lziV[tid] = lziv[lb + tid];

  f32x4 acc[32];
#pragma unroll
  for (int t = 0; t < 32; ++t) acc[t] = (f32x4){0.f, 0.f, 0.f, 0.f};

  __syncthreads();
  strip_body(tid, wj, wk, inner, su, sv, srtU, lziU, srtV, lziV,
             EU0, EV0, EU1, EV1, acc);

  // epilogue: dot with cost; C/D map col=lane&15, row=(lane>>4)*4+reg
  const float* cb = cost + (size_t)bh * 65536;
  float part = 0.f;
#pragma unroll
  for (int mt = 0; mt < 4; ++mt) {
#pragma unroll
    for (int nt = 0; nt < 8; ++nt) {
      const int col  = wk + nt*16 + m;
      const int rowb = j0 + wj + mt*16 + q*4;
      f32x4 a = acc[mt*8 + nt];
      part += a.x*cb[(size_t)(rowb+0)*256 + col] + a.y*cb[(size_t)(rowb+1)*256 + col]
            + a.z*cb[(size_t)(rowb+2)*256 + col] + a.w*cb[(size_t)(rowb+3)*256 + col];
    }
  }
#pragma unroll
  for (int o = 32; o > 0; o >>= 1) part += __shfl_down(part, o, 64);
  if (lane == 0) red[wave] = part;
  __syncthreads();
  if (tid == 0) atomicAdd(&swds[bh*64 + l], red[0] + red[1] + red[2] + red[3]);
}

// K4: weights = softmax(-TEMP*swds) over l
__global__ void weights_kernel(const float* __restrict__ swds, float* __restrict__ weights) {
  const int bh = blockIdx.x, t = threadIdx.x;
  float v = -TEMP * swds[bh*64 + t];
  float m = v;
#pragma unroll
  for (int o = 32; o > 0; o >>= 1) m = fmaxf(m, __shfl_xor(m, o, 64));
  float e = __expf(v - m);
  float ssum = e;
#pragma unroll
  for (int o = 32; o > 0; o >>= 1) ssum += __shfl_xor(ssum, o, 64);
  weights[bh*64 + t] = e / ssum;
}

// Pass 2: recompute Gamma with w_l folded (log2 into lziU); 8 l's per block
// accumulated in the MFMA acc; plain stores to per-lg partial buffer.
__global__ __launch_bounds__(256, 2) void pass2_kernel(
    const float* __restrict__ X, const float* __restrict__ Y,
    const float* __restrict__ srtu, const float* __restrict__ lziu,
    const float* __restrict__ srtv, const float* __restrict__ lziv,
    const float* __restrict__ wts, float* __restrict__ pws) {
  const int sb = blockIdx.x, lg = blockIdx.y, bh = blockIdx.z;
  const int j0 = sb * 128;
  const int tid = threadIdx.x, wave = tid >> 6, lane = tid & 63;
  const int wj = (wave & 1) * 64, wk = (wave >> 1) * 128;
  const int m = lane & 15, q = lane >> 4;
  const int inner = m*32 + (((q + (m >> 1)) & 3) << 3);

  __shared__ float su[128], sv[256];
  __shared__ float srtU[256], lziU[256], srtV[256], lziV[256];
  __shared__ __align__(16) unsigned short EU0[128*32], EU1[128*32];
  __shared__ __align__(16) unsigned short EV0[256*32], EV1[256*32];

  f32x4 acc[32];
#pragma unroll
  for (int t = 0; t < 32; ++t) acc[t] = (f32x4){0.f, 0.f, 0.f, 0.f};

#pragma unroll 1
  for (int li = 0; li < 8; ++li) {
    const int l  = lg*8 + li;
    const int lb = (bh*64 + l)*256;
    const float lw = __log2f(wts[bh*64 + l]);
    __syncthreads();                 // prev l's table readers done
    if (tid < 128) su[tid] = X[((size_t)bh*256 + j0 + tid)*64 + l];
    sv[tid]   = Y[((size_t)bh*256 + tid)*64 + l];
    srtU[tid] = srtu[lb + tid]; lziU[tid] = lziu[lb + tid] + lw;
    srtV[tid] = srtv[lb + tid]; lziV[tid] = lziv[lb + tid];
    __syncthreads();
    strip_body(tid, wj, wk, inner, su, sv, srtU, lziU, srtV, lziV,
               EU0, EV0, EU1, EV1, acc);
  }
  float* pb = pws + ((size_t)(lg*16 + bh)) * 65536;
#pragma unroll
  for (int mt = 0; mt < 4; ++mt) {
#pragma unroll
    for (int nt = 0; nt < 8; ++nt) {
      const int col  = wk + nt*16 + m;
      const int rowb = j0 + wj + mt*16 + q*4;
      f32x4 a = acc[mt*8 + nt];
      pb[(size_t)(rowb+0)*256 + col] = a.x;
      pb[(size_t)(rowb+1)*256 + col] = a.y;
      pb[(size_t)(rowb+2)*256 + col] = a.z;
      pb[(size_t)(rowb+3)*256 + col] = a.w;
    }
  }
}

// Reduce: out[bh] = sum_lg pws[lg][bh]
__global__ __launch_bounds__(256) void reduce_kernel(const float* __restrict__ pws,
                                                     float* __restrict__ out) {
  const int bh = blockIdx.y;
  const size_t p = ((size_t)blockIdx.x * 256 + threadIdx.x) * 4;
  float4 a = {0.f, 0.f, 0.f, 0.f};
#pragma unroll
  for (int lg = 0; lg < 8; ++lg) {
    float4 g = *(const float4*)&pws[((size_t)(lg*16 + bh)) * 65536 + p];
    a.x += g.x; a.y += g.y; a.z += g.z; a.w += g.w;
  }
  *(float4*)&out[((size_t)bh << 16) + p] = a;
}

extern "C" void kernel_launch(void* const* d_in, const int* in_sizes, int n_in,
                              void* d_out, int out_size, void* d_ws, size_t ws_size,
                              hipStream_t stream) {
  (void)in_sizes; (void)n_in; (void)out_size; (void)ws_size;
  const float* X = (const float*)d_in[0];
  const float* Y = (const float*)d_in[1];
  float* out = (float*)d_out;
  float* ws  = (float*)d_ws;
  float* cost  = ws;                    // 1048576
  float* srtu  = ws   + 1048576;
  float* lziu  = srtu + 262144;
  float* srtv  = lziu + 262144;
  float* lziv  = srtv + 262144;
  float* swds  = lziv + 262144;         // 1024
  float* wts   = swds + 1024;           // 1024
  float* pws   = wts  + 1024;           // 8388608 (34 MB; ws known >= 142 MB from r4)

  hipMemsetAsync(swds, 0, 1024 * sizeof(float), stream);
  cost_kernel   <<<dim3(256, 16),   256, 0, stream>>>(X, Y, cost);
  sortz_kernel  <<<dim3(64, 16, 2), 256, 0, stream>>>(X, Y, srtu, lziu, srtv, lziv);
  pass1_kernel  <<<dim3(2, 64, 16), 256, 0, stream>>>(X, Y, cost, srtu, lziu, srtv, lziv, swds);
  weights_kernel<<<dim3(16),         64, 0, stream>>>(swds, wts);
  pass2_kernel  <<<dim3(2, 8, 16),  256, 0, stream>>>(X, Y, srtu, lziu, srtv, lziv, wts, pws);
  reduce_kernel <<<dim3(64, 16),    256, 0, stream>>>(pws, out);
}

// Round 6
// 216.994 us; speedup vs baseline: 1.3189x; 1.3189x over previous
//
#include <hip/hip_runtime.h>
#include <math.h>

#define INV_TAU 1000.0f
#define TEMP    0.1f
#define CEXP    -1442.6950408889634f   // -1000 * log2(e)

// Problem: B=2,H=8 -> BH=16; N=256; L=64.  X,Y: [BH,256,64] f32. out: [BH,256,256] f32.
//
// Round 6: pass1 (pipelined fp16-MFMA Gamma strips) also stores Gamma as bf16
// in fragment-linear layout [group][l][lane] (512B-contiguous per frag store);
// pass2/reduce replaced by streaming wsum over the stored Gamma. su/sv moved
// to registers -> LDS 52KB -> 3 blocks/CU resident.
//
// ws (floats): cost[16*65536] | srtu | lziu | srtv | lziv (262144 ea) |
//              swds[1024] | wts[1024] | gamma bf16-in-uint2 [4096][64][64] (134MB)
// total 142.6 MB (same as r4's verified-available need_bytes).

typedef __attribute__((ext_vector_type(8))) _Float16 half8;
typedef __attribute__((ext_vector_type(8))) short short8;
typedef __attribute__((ext_vector_type(4))) float f32x4;

__device__ __forceinline__ float fexp2(float x) { return __builtin_amdgcn_exp2f(x); }

__device__ __forceinline__ half8 ldsh8(const unsigned short* p) {
  return __builtin_bit_cast(half8, *(const short8*)p);
}

__device__ __forceinline__ unsigned bf16r(float f) {   // bf16 RNE, as low 16 bits
  unsigned u = __float_as_uint(f);
  return (u + 0x7FFFu + ((u >> 16) & 1u)) >> 16;
}

// swizzled short-offset of (row, group g of 8 i's) in a 32-short-per-row table
__device__ __forceinline__ int tswz(int row, int g) {
  return row * 32 + (((g + (row >> 1)) & 3) << 3);
}

// K1: cost[bh][j][k] = sqrt(max(|Xj|^2+|Yk|^2-2Xj.Yk, 1e-12))
__global__ __launch_bounds__(256) void cost_kernel(const float* __restrict__ X,
                                                   const float* __restrict__ Y,
                                                   float* __restrict__ cost) {
  const int j = blockIdx.x, bh = blockIdx.y, k = threadIdx.x;
  __shared__ __align__(16) float xr[64];
  if (k < 64) xr[k] = X[((size_t)bh*256 + j)*64 + k];
  __syncthreads();
  const float4* yp = (const float4*)(Y + ((size_t)bh*256 + k)*64);
  const float4* xp = (const float4*)xr;
  float dot = 0.f, x2 = 0.f, y2 = 0.f;
#pragma unroll
  for (int t = 0; t < 16; ++t) {
    float4 yv = yp[t], xv = xp[t];
    dot += xv.x*yv.x + xv.y*yv.y + xv.z*yv.z + xv.w*yv.w;
    x2  += xv.x*xv.x + xv.y*xv.y + xv.z*xv.z + xv.w*xv.w;
    y2  += yv.x*yv.x + yv.y*yv.y + yv.z*yv.z + yv.w*yv.w;
  }
  float c = x2 + y2 - 2.f*dot;
  cost[((size_t)bh*256 + j)*256 + k] = sqrtf(fmaxf(c, 1e-12f));
}

// K2: shuffle-bitonic descending sort + banded Z (tail < e^-60 dropped).
__global__ __launch_bounds__(256) void sortz_kernel(const float* __restrict__ X,
                                                    const float* __restrict__ Y,
                                                    float* __restrict__ srtu, float* __restrict__ lziu,
                                                    float* __restrict__ srtv, float* __restrict__ lziv) {
  const int l = blockIdx.x, bh = blockIdx.y, tid = threadIdx.x;
  const float* S = blockIdx.z ? Y : X;
  float* so = blockIdx.z ? srtv : srtu;
  float* zo = blockIdx.z ? lziv : lziu;
  __shared__ float s[256];
  float v = S[((size_t)bh*256 + tid)*64 + l];
#pragma unroll
  for (int k = 2; k <= 256; k <<= 1) {
#pragma unroll
    for (int j = k >> 1; j > 0; j >>= 1) {
      float o;
      if (j >= 64) {
        s[tid] = v; __syncthreads();
        o = s[tid ^ j]; __syncthreads();
      } else {
        o = __shfl_xor(v, j, 64);
      }
      const bool up    = ((tid & k) == 0);
      const bool lower = ((tid & j) == 0);
      float mn = fminf(v, o), mx = fmaxf(v, o);
      v = (up == lower) ? mn : mx;
    }
  }
  s[tid] = v; __syncthreads();
  const int jc = 255 - tid;
  const float sv = s[jc];
  const int lo = jc > 48 ? jc - 48 : 0;
  const int hi = jc < 207 ? jc + 48 : 255;
  float z = 0.f;
  for (int jj = lo; jj <= hi; ++jj) { float d = s[jj] - sv; z += fexp2(d*d*CEXP); }
  const int base = (bh*64 + l)*256 + tid;
  so[base] = sv; zo[base] = -__log2f(z);
}

// ---- staging: one 32-i slab of the fp16 exp tables (swizzled layout) ----
// su_val: this thread's X row value (row r=t&127 of the j-strip);
// sv0/sv1: Y rows r and r+128.
__device__ __forceinline__ void stage_slab(int t, int ib,
                                           float su_val, float sv0, float sv1,
                                           const float* __restrict__ srtU, const float* __restrict__ lziU,
                                           const float* __restrict__ srtV, const float* __restrict__ lziV,
                                           unsigned short* __restrict__ EU,
                                           unsigned short* __restrict__ EV) {
  const int r  = t & 127;
  const int gp = (t >> 7) << 1;
  const int i0 = ib + (gp << 3);
  {
    float e[16];
#pragma unroll
    for (int ii = 0; ii < 16; ++ii) {
      float d = su_val - srtU[i0 + ii];
      e[ii] = fexp2(fmaf(d*d, CEXP, lziU[i0 + ii]));
    }
#pragma unroll
    for (int gg = 0; gg < 2; ++gg) {
      uint4 w;
      w.x = __builtin_bit_cast(unsigned, __builtin_amdgcn_cvt_pkrtz(e[gg*8+0], e[gg*8+1]));
      w.y = __builtin_bit_cast(unsigned, __builtin_amdgcn_cvt_pkrtz(e[gg*8+2], e[gg*8+3]));
      w.z = __builtin_bit_cast(unsigned, __builtin_amdgcn_cvt_pkrtz(e[gg*8+4], e[gg*8+5]));
      w.w = __builtin_bit_cast(unsigned, __builtin_amdgcn_cvt_pkrtz(e[gg*8+6], e[gg*8+7]));
      *(uint4*)&EU[tswz(r, gp + gg)] = w;
    }
  }
#pragma unroll
  for (int rr = 0; rr < 2; ++rr) {
    const int row = r + rr*128;
    const float v = rr ? sv1 : sv0;
    float e[16];
#pragma unroll
    for (int ii = 0; ii < 16; ++ii) {
      float d = v - srtV[i0 + ii];
      e[ii] = fexp2(fmaf(d*d, CEXP, lziV[i0 + ii]));
    }
#pragma unroll
    for (int gg = 0; gg < 2; ++gg) {
      uint4 w;
      w.x = __builtin_bit_cast(unsigned, __builtin_amdgcn_cvt_pkrtz(e[gg*8+0], e[gg*8+1]));
      w.y = __builtin_bit_cast(unsigned, __builtin_amdgcn_cvt_pkrtz(e[gg*8+2], e[gg*8+3]));
      w.z = __builtin_bit_cast(unsigned, __builtin_amdgcn_cvt_pkrtz(e[gg*8+4], e[gg*8+5]));
      w.w = __builtin_bit_cast(unsigned, __builtin_amdgcn_cvt_pkrtz(e[gg*8+6], e[gg*8+7]));
      *(uint4*)&EV[tswz(row, gp + gg)] = w;
    }
  }
}

// Pass 1: per (strip sb, l, bh): Gamma strip (128j x 256k) via pipelined fp16
// MFMA; dot with cost -> swds (atomic); store Gamma bf16 fragment-linear.
__global__ __launch_bounds__(256, 2) void pass1_kernel(
    const float* __restrict__ X, const float* __restrict__ Y,
    const float* __restrict__ cost,
    const float* __restrict__ srtu, const float* __restrict__ lziu,
    const float* __restrict__ srtv, const float* __restrict__ lziv,
    float* __restrict__ swds, uint2* __restrict__ gamma) {
  const int sb = blockIdx.x, l = blockIdx.y, bh = blockIdx.z;
  const int j0 = sb * 128;
  const int tid = threadIdx.x, wave = tid >> 6, lane = tid & 63;
  const int wj = (wave & 1) * 64, wk = (wave >> 1) * 128;
  const int m = lane & 15, q = lane >> 4;
  const int inner = m*32 + (((q + (m >> 1)) & 3) << 3);

  __shared__ float srtU[256], lziU[256], srtV[256], lziV[256];
  __shared__ __align__(16) unsigned short EU0[128*32], EU1[128*32];
  __shared__ __align__(16) unsigned short EV0[256*32], EV1[256*32];
  // LDS total: 4KB + 16KB + 32KB = 52KB -> 3 blocks/CU

  const int lb = (bh*64 + l)*256;
  const int r  = tid & 127;
  const float su_val = X[((size_t)bh*256 + j0 + r)*64 + l];
  const float sv0    = Y[((size_t)bh*256 + r)*64 + l];
  const float sv1    = Y[((size_t)bh*256 + r + 128)*64 + l];
  srtU[tid] = srtu[lb + tid]; lziU[tid] = lziu[lb + tid];
  srtV[tid] = srtv[lb + tid]; lziV[tid] = lziv[lb + tid];

  f32x4 acc[32];
#pragma unroll
  for (int t = 0; t < 32; ++t) acc[t] = (f32x4){0.f, 0.f, 0.f, 0.f};

  __syncthreads();
  stage_slab(tid, 0, su_val, sv0, sv1, srtU, lziU, srtV, lziV, EU0, EV0);
  __syncthreads();
#pragma unroll 1
  for (int s = 0; s < 8; ++s) {
    const unsigned short* EUc = (s & 1) ? EU1 : EU0;
    const unsigned short* EVc = (s & 1) ? EV1 : EV0;
    unsigned short* EUn = (s & 1) ? EU0 : EU1;
    unsigned short* EVn = (s & 1) ? EV0 : EV1;
    half8 B[8], A[4];
#pragma unroll
    for (int nt = 0; nt < 8; ++nt) B[nt] = ldsh8(&EVc[(wk + nt*16)*32 + inner]);
#pragma unroll
    for (int mt = 0; mt < 4; ++mt) A[mt] = ldsh8(&EUc[(wj + mt*16)*32 + inner]);
    if (s < 7)
      stage_slab(tid, (s+1)*32, su_val, sv0, sv1, srtU, lziU, srtV, lziV, EUn, EVn);
#pragma unroll
    for (int mt = 0; mt < 4; ++mt)
#pragma unroll
      for (int nt = 0; nt < 8; ++nt)
        acc[mt*8+nt] = __builtin_amdgcn_mfma_f32_16x16x32_f16(A[mt], B[nt], acc[mt*8+nt], 0, 0, 0);
    __syncthreads();
  }

  // epilogue: dot with cost + bf16 Gamma store (fragment-linear, coalesced).
  // C/D map: col=lane&15, row=(lane>>4)*4+reg
  const float* cb = cost + (size_t)bh * 65536;
  const int gbase = ((bh*2 + sb)*4 + wave) * 32;     // group = gbase + frag
  float part = 0.f;
#pragma unroll
  for (int mt = 0; mt < 4; ++mt) {
#pragma unroll
    for (int nt = 0; nt < 8; ++nt) {
      const int col  = wk + nt*16 + m;
      const int rowb = j0 + wj + mt*16 + q*4;
      f32x4 a = acc[mt*8 + nt];
      part += a.x*cb[(size_t)(rowb+0)*256 + col] + a.y*cb[(size_t)(rowb+1)*256 + col]
            + a.z*cb[(size_t)(rowb+2)*256 + col] + a.w*cb[(size_t)(rowb+3)*256 + col];
      uint2 pk;
      pk.x = bf16r(a.x) | (bf16r(a.y) << 16);
      pk.y = bf16r(a.z) | (bf16r(a.w) << 16);
      gamma[((size_t)(gbase + mt*8 + nt)*64 + l)*64 + lane] = pk;
    }
  }
#pragma unroll
  for (int o = 32; o > 0; o >>= 1) part += __shfl_down(part, o, 64);
  if (lane == 0) atomicAdd(&swds[bh*64 + l], part);
}

// K4: weights = softmax(-TEMP*swds) over l
__global__ void weights_kernel(const float* __restrict__ swds, float* __restrict__ weights) {
  const int bh = blockIdx.x, t = threadIdx.x;
  float v = -TEMP * swds[bh*64 + t];
  float m = v;
#pragma unroll
  for (int o = 32; o > 0; o >>= 1) m = fmaxf(m, __shfl_xor(m, o, 64));
  float e = __expf(v - m);
  float ssum = e;
#pragma unroll
  for (int o = 32; o > 0; o >>= 1) ssum += __shfl_xor(ssum, o, 64);
  weights[bh*64 + t] = e / ssum;
}

// wsum: out = sum_l w_l * Gamma_l.  One wave per group: streams its 32KB chunk
// (64 l x 512B contiguous), then writes 4 canonical out elements per lane.
__global__ __launch_bounds__(256) void wsum_kernel(const uint2* __restrict__ g,
                                                   const float* __restrict__ wts,
                                                   float* __restrict__ out) {
  const int wv = threadIdx.x >> 6, lane = threadIdx.x & 63;
  const int group = blockIdx.x * 4 + wv;          // 0..4095
  const int frag = group & 31;
  const int gw   = group >> 5;                    // (bh*2+sb)*4 + wave
  const int wave = gw & 3;
  const int sb   = (gw >> 2) & 1;
  const int bh   = gw >> 3;                       // uniform within block
  __shared__ float w[64];
  if (threadIdx.x < 64) w[threadIdx.x] = wts[bh*64 + threadIdx.x];
  __syncthreads();
  const uint2* gp = g + (size_t)group*4096 + lane;
  float4 acc = {0.f, 0.f, 0.f, 0.f};
#pragma unroll 8
  for (int l = 0; l < 64; ++l) {
    uint2 pk = gp[l*64];
    float wl = w[l];
    acc.x += wl * __uint_as_float(pk.x << 16);
    acc.y += wl * __uint_as_float(pk.x & 0xFFFF0000u);
    acc.z += wl * __uint_as_float(pk.y << 16);
    acc.w += wl * __uint_as_float(pk.y & 0xFFFF0000u);
  }
  const int mt = frag >> 3, nt = frag & 7;
  const int m = lane & 15, q = lane >> 4;
  const int row = sb*128 + (wave & 1)*64 + mt*16 + q*4;
  const int col = (wave >> 1)*128 + nt*16 + m;
  float* ob = out + ((size_t)bh*256 + row)*256 + col;
  ob[0]   = acc.x;
  ob[256] = acc.y;
  ob[512] = acc.z;
  ob[768] = acc.w;
}

extern "C" void kernel_launch(void* const* d_in, const int* in_sizes, int n_in,
                              void* d_out, int out_size, void* d_ws, size_t ws_size,
                              hipStream_t stream) {
  (void)in_sizes; (void)n_in; (void)out_size; (void)ws_size;
  const float* X = (const float*)d_in[0];
  const float* Y = (const float*)d_in[1];
  float* out = (float*)d_out;
  float* ws  = (float*)d_ws;
  float* cost  = ws;                    // 1048576
  float* srtu  = ws   + 1048576;
  float* lziu  = srtu + 262144;
  float* srtv  = lziu + 262144;
  float* lziv  = srtv + 262144;
  float* swds  = lziv + 262144;         // 1024
  float* wts   = swds + 1024;           // 1024
  uint2* gamma = (uint2*)(wts + 1024);  // 4096 groups x 64 l x 64 lanes x 8B = 134MB
                                        // total need = 142.6MB (verified available in r4)

  hipMemsetAsync(swds, 0, 1024 * sizeof(float), stream);
  cost_kernel   <<<dim3(256, 16),   256, 0, stream>>>(X, Y, cost);
  sortz_kernel  <<<dim3(64, 16, 2), 256, 0, stream>>>(X, Y, srtu, lziu, srtv, lziv);
  pass1_kernel  <<<dim3(2, 64, 16), 256, 0, stream>>>(X, Y, cost, srtu, lziu, srtv, lziv,
                                                      swds, gamma);
  weights_kernel<<<dim3(16),         64, 0, stream>>>(swds, wts);
  wsum_kernel   <<<dim3(1024),      256, 0, stream>>>(gamma, wts, out);
}

// Round 7
// 210.411 us; speedup vs baseline: 1.3602x; 1.0313x over previous
//
#include <hip/hip_runtime.h>
#include <math.h>

#define INV_TAU 1000.0f
#define TEMP    0.1f
#define CEXP    -1442.6950408889634f   // -1000 * log2(e)

// Problem: B=2,H=8 -> BH=16; N=256; L=64.  X,Y: [BH,256,64] f32. out: [BH,256,256] f32.
//
// Round 7: 64x64 wave tiles (acc[16]=64 AGPR) + __launch_bounds__(256,3) ->
// 3 waves/SIMD (was 2: r6's 120 VGPR + 128 AGPR = 248 = unified-file bound).
// 128x128 Gamma tiles, grid 4096. prep = cost+sortz merged; wsum recomputes
// softmax from per-tile swds partials (no atomics, no memset, 3 launches).
//
// ws (floats): cost[1048576] | srtu|lziu|srtv|lziv (262144 ea) |
//              parts[4096] | gamma uint2[4096*64*64] (134MB)

typedef __attribute__((ext_vector_type(8))) _Float16 half8;
typedef __attribute__((ext_vector_type(8))) short short8;
typedef __attribute__((ext_vector_type(4))) float f32x4;

__device__ __forceinline__ float fexp2(float x) { return __builtin_amdgcn_exp2f(x); }

__device__ __forceinline__ half8 ldsh8(const unsigned short* p) {
  return __builtin_bit_cast(half8, *(const short8*)p);
}

__device__ __forceinline__ unsigned bf16r(float f) {   // bf16 RNE, low 16 bits
  unsigned u = __float_as_uint(f);
  return (u + 0x7FFFu + ((u >> 16) & 1u)) >> 16;
}

// swizzled short-offset of (row, oct g) in a 32-short-per-row table
__device__ __forceinline__ int tswz(int row, int g) {
  return row * 32 + (((g + (row >> 1)) & 3) << 3);
}

// prep: blockIdx.x < 4096 -> cost tile; else sortz for (l, bh, X/Y).
__global__ __launch_bounds__(256) void prep_kernel(const float* __restrict__ X,
                                                   const float* __restrict__ Y,
                                                   float* __restrict__ cost,
                                                   float* __restrict__ srtu, float* __restrict__ lziu,
                                                   float* __restrict__ srtv, float* __restrict__ lziv) {
  __shared__ __align__(16) float smem[256];
  const int tid = threadIdx.x;
  if (blockIdx.x < 4096) {
    const int j = blockIdx.x & 255, bh = blockIdx.x >> 8;
    if (tid < 64) smem[tid] = X[((size_t)bh*256 + j)*64 + tid];
    __syncthreads();
    const float4* yp = (const float4*)(Y + ((size_t)bh*256 + tid)*64);
    const float4* xp = (const float4*)smem;
    float dot = 0.f, x2 = 0.f, y2 = 0.f;
#pragma unroll
    for (int t = 0; t < 16; ++t) {
      float4 yv = yp[t], xv = xp[t];
      dot += xv.x*yv.x + xv.y*yv.y + xv.z*yv.z + xv.w*yv.w;
      x2  += xv.x*xv.x + xv.y*xv.y + xv.z*xv.z + xv.w*xv.w;
      y2  += yv.x*yv.x + yv.y*yv.y + yv.z*yv.z + yv.w*yv.w;
    }
    float c = x2 + y2 - 2.f*dot;
    cost[((size_t)bh*256 + j)*256 + tid] = sqrtf(fmaxf(c, 1e-12f));
  } else {
    const int idx = blockIdx.x - 4096;
    const int l = idx & 63, bh = (idx >> 6) & 15, uv = idx >> 10;
    const float* S = uv ? Y : X;
    float* so = uv ? srtv : srtu;
    float* zo = uv ? lziv : lziu;
    float v = S[((size_t)bh*256 + tid)*64 + l];
#pragma unroll
    for (int k = 2; k <= 256; k <<= 1) {
#pragma unroll
      for (int j = k >> 1; j > 0; j >>= 1) {
        float o;
        if (j >= 64) {
          smem[tid] = v; __syncthreads();
          o = smem[tid ^ j]; __syncthreads();
        } else {
          o = __shfl_xor(v, j, 64);
        }
        const bool up    = ((tid & k) == 0);
        const bool lower = ((tid & j) == 0);
        float mn = fminf(v, o), mx = fmaxf(v, o);
        v = (up == lower) ? mn : mx;
      }
    }
    smem[tid] = v; __syncthreads();
    const int jc = 255 - tid;
    const float sv = smem[jc];
    const int lo = jc > 48 ? jc - 48 : 0;
    const int hi = jc < 207 ? jc + 48 : 255;
    float z = 0.f;
    for (int jj = lo; jj <= hi; ++jj) { float d = smem[jj] - sv; z += fexp2(d*d*CEXP); }
    const int base = (bh*64 + l)*256 + tid;
    so[base] = sv; zo[base] = -__log2f(z);
  }
}

// stage one 32-i slab of 128-row fp16 exp tables (swizzled, conflict-free).
// thread t: row r=t&127, octs gp,gp+1 (16 i's) of both EU and EV.
__device__ __forceinline__ void stage_slab(int t, int ib, float uval, float vval,
                                           const float* __restrict__ srtU, const float* __restrict__ lziU,
                                           const float* __restrict__ srtV, const float* __restrict__ lziV,
                                           unsigned short* __restrict__ EU,
                                           unsigned short* __restrict__ EV) {
  const int r  = t & 127;
  const int gp = (t >> 7) << 1;
  const int i0 = ib + (gp << 3);
  {
    float e[16];
#pragma unroll
    for (int ii = 0; ii < 16; ++ii) {
      float d = uval - srtU[i0 + ii];
      e[ii] = fexp2(fmaf(d*d, CEXP, lziU[i0 + ii]));
    }
#pragma unroll
    for (int gg = 0; gg < 2; ++gg) {
      uint4 w;
      w.x = __builtin_bit_cast(unsigned, __builtin_amdgcn_cvt_pkrtz(e[gg*8+0], e[gg*8+1]));
      w.y = __builtin_bit_cast(unsigned, __builtin_amdgcn_cvt_pkrtz(e[gg*8+2], e[gg*8+3]));
      w.z = __builtin_bit_cast(unsigned, __builtin_amdgcn_cvt_pkrtz(e[gg*8+4], e[gg*8+5]));
      w.w = __builtin_bit_cast(unsigned, __builtin_amdgcn_cvt_pkrtz(e[gg*8+6], e[gg*8+7]));
      *(uint4*)&EU[tswz(r, gp + gg)] = w;
    }
  }
  {
    float e[16];
#pragma unroll
    for (int ii = 0; ii < 16; ++ii) {
      float d = vval - srtV[i0 + ii];
      e[ii] = fexp2(fmaf(d*d, CEXP, lziV[i0 + ii]));
    }
#pragma unroll
    for (int gg = 0; gg < 2; ++gg) {
      uint4 w;
      w.x = __builtin_bit_cast(unsigned, __builtin_amdgcn_cvt_pkrtz(e[gg*8+0], e[gg*8+1]));
      w.y = __builtin_bit_cast(unsigned, __builtin_amdgcn_cvt_pkrtz(e[gg*8+2], e[gg*8+3]));
      w.z = __builtin_bit_cast(unsigned, __builtin_amdgcn_cvt_pkrtz(e[gg*8+4], e[gg*8+5]));
      w.w = __builtin_bit_cast(unsigned, __builtin_amdgcn_cvt_pkrtz(e[gg*8+6], e[gg*8+7]));
      *(uint4*)&EV[tswz(r, gp + gg)] = w;
    }
  }
}

// Pass 1: per (tile, l, bh): 128x128 Gamma tile via pipelined fp16 MFMA
// (64x64 wave tiles, acc[16]); dot with cost -> parts; Gamma bf16 store
// fragment-linear [group][l][lane].
__global__ __launch_bounds__(256, 3) void pass1_kernel(
    const float* __restrict__ X, const float* __restrict__ Y,
    const float* __restrict__ cost,
    const float* __restrict__ srtu, const float* __restrict__ lziu,
    const float* __restrict__ srtv, const float* __restrict__ lziv,
    float* __restrict__ parts, uint2* __restrict__ gamma) {
  const int tile = blockIdx.x, l = blockIdx.y, bh = blockIdx.z;
  const int j0 = (tile >> 1) * 128, k0 = (tile & 1) * 128;
  const int tid = threadIdx.x, wave = tid >> 6, lane = tid & 63;
  const int wj = (wave & 1) * 64, wk = (wave >> 1) * 64;
  const int m = lane & 15, q = lane >> 4;
  const int inner = m*32 + (((q + (m >> 1)) & 3) << 3);

  __shared__ float srtU[256], lziU[256], srtV[256], lziV[256];
  __shared__ __align__(16) unsigned short EU0[128*32], EU1[128*32];
  __shared__ __align__(16) unsigned short EV0[128*32], EV1[128*32];
  __shared__ float red[4];
  // LDS: 4KB + 4x8KB = 36KB

  const int lb = (bh*64 + l)*256;
  const int r  = tid & 127;
  const float uval = X[((size_t)bh*256 + j0 + r)*64 + l];
  const float vval = Y[((size_t)bh*256 + k0 + r)*64 + l];
  srtU[tid] = srtu[lb + tid]; lziU[tid] = lziu[lb + tid];
  srtV[tid] = srtv[lb + tid]; lziV[tid] = lziv[lb + tid];

  f32x4 acc[16];
#pragma unroll
  for (int t = 0; t < 16; ++t) acc[t] = (f32x4){0.f, 0.f, 0.f, 0.f};

  __syncthreads();
  stage_slab(tid, 0, uval, vval, srtU, lziU, srtV, lziV, EU0, EV0);
  __syncthreads();
#pragma unroll 1
  for (int s = 0; s < 8; ++s) {
    const unsigned short* EUc = (s & 1) ? EU1 : EU0;
    const unsigned short* EVc = (s & 1) ? EV1 : EV0;
    unsigned short* EUn = (s & 1) ? EU0 : EU1;
    unsigned short* EVn = (s & 1) ? EV0 : EV1;
    half8 A[4], B[4];
#pragma unroll
    for (int mt = 0; mt < 4; ++mt) A[mt] = ldsh8(&EUc[(wj + mt*16)*32 + inner]);
#pragma unroll
    for (int nt = 0; nt < 4; ++nt) B[nt] = ldsh8(&EVc[(wk + nt*16)*32 + inner]);
    if (s < 7)
      stage_slab(tid, (s+1)*32, uval, vval, srtU, lziU, srtV, lziV, EUn, EVn);
#pragma unroll
    for (int mt = 0; mt < 4; ++mt)
#pragma unroll
      for (int nt = 0; nt < 4; ++nt)
        acc[mt*4+nt] = __builtin_amdgcn_mfma_f32_16x16x32_f16(A[mt], B[nt], acc[mt*4+nt], 0, 0, 0);
    __syncthreads();
  }

  // epilogue: dot with cost + coalesced bf16 Gamma store.
  // C/D map: col=lane&15, row=(lane>>4)*4+reg
  const float* cb = cost + (size_t)bh * 65536;
  const int gbase = ((bh*4 + tile)*4 + wave) * 16;
  float part = 0.f;
#pragma unroll
  for (int mt = 0; mt < 4; ++mt) {
#pragma unroll
    for (int nt = 0; nt < 4; ++nt) {
      const int col  = k0 + wk + nt*16 + m;
      const int rowb = j0 + wj + mt*16 + q*4;
      f32x4 a = acc[mt*4 + nt];
      part += a.x*cb[(size_t)(rowb+0)*256 + col] + a.y*cb[(size_t)(rowb+1)*256 + col]
            + a.z*cb[(size_t)(rowb+2)*256 + col] + a.w*cb[(size_t)(rowb+3)*256 + col];
      uint2 pk;
      pk.x = bf16r(a.x) | (bf16r(a.y) << 16);
      pk.y = bf16r(a.z) | (bf16r(a.w) << 16);
      gamma[((size_t)(gbase + mt*4 + nt)*64 + l)*64 + lane] = pk;
    }
  }
#pragma unroll
  for (int o = 32; o > 0; o >>= 1) part += __shfl_down(part, o, 64);
  if (lane == 0) red[wave] = part;
  __syncthreads();
  if (tid == 0) parts[(size_t)tile*1024 + bh*64 + l] = red[0] + red[1] + red[2] + red[3];
}

// wsum: per block, recompute softmax weights from the 4 swds partials, then
// out = sum_l w_l * Gamma_l (each wave streams one 32KB fragment-linear chunk).
__global__ __launch_bounds__(256) void wsum_kernel(const uint2* __restrict__ g,
                                                   const float* __restrict__ parts,
                                                   float* __restrict__ out) {
  const int wv = threadIdx.x >> 6, lane = threadIdx.x & 63;
  const int bh = blockIdx.x >> 6;                 // 64 blocks per bh
  __shared__ float w[64];
  if (wv == 0) {
    float s = parts[bh*64 + lane] + parts[1024 + bh*64 + lane]
            + parts[2048 + bh*64 + lane] + parts[3072 + bh*64 + lane];
    float v = -TEMP * s;
    float mx = v;
#pragma unroll
    for (int o = 32; o > 0; o >>= 1) mx = fmaxf(mx, __shfl_xor(v = fmaxf(v, mx), o, 64));
    // (recompute cleanly to avoid subtle shfl aliasing)
    mx = -TEMP * s;
    float vv = mx;
#pragma unroll
    for (int o = 32; o > 0; o >>= 1) vv = fmaxf(vv, __shfl_xor(vv, o, 64));
    float e = fexp2((-TEMP * s - vv) * 1.4426950408889634f);
    float ssum = e;
#pragma unroll
    for (int o = 32; o > 0; o >>= 1) ssum += __shfl_xor(ssum, o, 64);
    w[lane] = e / ssum;
  }
  __syncthreads();
  const int group = blockIdx.x * 4 + wv;
  const uint2* gp = g + (size_t)group*4096 + lane;
  float4 acc = {0.f, 0.f, 0.f, 0.f};
#pragma unroll 8
  for (int l = 0; l < 64; ++l) {
    uint2 pk = gp[l*64];
    float wl = w[l];
    acc.x += wl * __uint_as_float(pk.x << 16);
    acc.y += wl * __uint_as_float(pk.x & 0xFFFF0000u);
    acc.z += wl * __uint_as_float(pk.y << 16);
    acc.w += wl * __uint_as_float(pk.y & 0xFFFF0000u);
  }
  const int frag = group & 15;
  const int idx  = group >> 4;                    // (bh*4+tile)*4+wave
  const int wave = idx & 3, tile = (idx >> 2) & 3;
  const int mt = frag >> 2, nt = frag & 3;
  const int m = lane & 15, q = lane >> 4;
  const int row = (tile >> 1)*128 + (wave & 1)*64 + mt*16 + q*4;
  const int col = (tile & 1)*128 + (wave >> 1)*64 + nt*16 + m;
  float* ob = out + ((size_t)bh*256 + row)*256 + col;
  ob[0]   = acc.x;
  ob[256] = acc.y;
  ob[512] = acc.z;
  ob[768] = acc.w;
}

extern "C" void kernel_launch(void* const* d_in, const int* in_sizes, int n_in,
                              void* d_out, int out_size, void* d_ws, size_t ws_size,
                              hipStream_t stream) {
  (void)in_sizes; (void)n_in; (void)out_size; (void)ws_size;
  const float* X = (const float*)d_in[0];
  const float* Y = (const float*)d_in[1];
  float* out = (float*)d_out;
  float* ws  = (float*)d_ws;
  float* cost  = ws;                    // 1048576
  float* srtu  = ws   + 1048576;
  float* lziu  = srtu + 262144;
  float* srtv  = lziu + 262144;
  float* lziv  = srtv + 262144;
  float* parts = lziv + 262144;         // 4096 (written, not accumulated: no memset)
  uint2* gamma = (uint2*)(parts + 4096);// 4096 groups x 64 l x 64 lanes x 8B = 134MB

  prep_kernel <<<dim3(6144),      256, 0, stream>>>(X, Y, cost, srtu, lziu, srtv, lziv);
  pass1_kernel<<<dim3(4, 64, 16), 256, 0, stream>>>(X, Y, cost, srtu, lziu, srtv, lziv,
                                                    parts, gamma);
  wsum_kernel <<<dim3(1024),      256, 0, stream>>>(gamma, parts, out);
}

// Round 9
// 169.495 us; speedup vs baseline: 1.6885x; 1.2414x over previous
//
#include <hip/hip_runtime.h>
#include <math.h>

#define INV_TAU 1000.0f
#define TEMP    0.1f
#define CEXP    -1442.6950408889634f   // -1000 * log2(e)

// Problem: B=2,H=8 -> BH=16; N=256; L=64.  X,Y: [BH,256,64] f32. out: [BH,256,256] f32.
//
// Round 8b: r8 with the NT-builtin type fix (native ext_vector u32x2 instead of
// HIP_vector_type uint2). (1) pass1 register diet + __launch_bounds__(256,4) ->
// target 64 VGPR + 64 AGPR = 128 = 4 waves/SIMD; (2) non-temporal gamma
// stores/loads; (3) prep cost tiles 4 j-rows/block.
//
// ws (floats): cost[1048576] | srtu|lziu|srtv|lziv (262144 ea) |
//              parts[4096] | gamma u32x2[4096*64*64] (134MB)

typedef __attribute__((ext_vector_type(8))) _Float16 half8;
typedef __attribute__((ext_vector_type(8))) short short8;
typedef __attribute__((ext_vector_type(4))) float f32x4;
typedef __attribute__((ext_vector_type(2))) unsigned int u32x2;

__device__ __forceinline__ float fexp2(float x) { return __builtin_amdgcn_exp2f(x); }

__device__ __forceinline__ half8 ldsh8(const unsigned short* p) {
  return __builtin_bit_cast(half8, *(const short8*)p);
}

__device__ __forceinline__ unsigned bf16r(float f) {   // bf16 RNE, low 16 bits
  unsigned u = __float_as_uint(f);
  return (u + 0x7FFFu + ((u >> 16) & 1u)) >> 16;
}

// swizzled short-offset of (row, oct g) in a 32-short-per-row table
__device__ __forceinline__ int tswz(int row, int g) {
  return row * 32 + (((g + (row >> 1)) & 3) << 3);
}

// prep: blockIdx.x < 1024 -> cost quad-row tile; else sortz for (l, bh, X/Y).
__global__ __launch_bounds__(256) void prep_kernel(const float* __restrict__ X,
                                                   const float* __restrict__ Y,
                                                   float* __restrict__ cost,
                                                   float* __restrict__ srtu, float* __restrict__ lziu,
                                                   float* __restrict__ srtv, float* __restrict__ lziv) {
  __shared__ __align__(16) float smem[256];
  const int tid = threadIdx.x;
  if (blockIdx.x < 1024) {
    const int jq = blockIdx.x & 63, bh = blockIdx.x >> 6;
    const int j0 = jq * 4;
    smem[tid] = X[((size_t)bh*256 + j0 + (tid >> 6))*64 + (tid & 63)];
    __syncthreads();
    const float4* yp = (const float4*)(Y + ((size_t)bh*256 + tid)*64);
    float dot[4] = {0.f,0.f,0.f,0.f}, x2[4] = {0.f,0.f,0.f,0.f}, y2 = 0.f;
#pragma unroll
    for (int t = 0; t < 16; ++t) {
      float4 yv = yp[t];
      y2 += yv.x*yv.x + yv.y*yv.y + yv.z*yv.z + yv.w*yv.w;
#pragma unroll
      for (int r = 0; r < 4; ++r) {
        float4 xv = ((const float4*)(smem + r*64))[t];
        dot[r] += xv.x*yv.x + xv.y*yv.y + xv.z*yv.z + xv.w*yv.w;
        x2[r]  += xv.x*xv.x + xv.y*xv.y + xv.z*xv.z + xv.w*xv.w;
      }
    }
#pragma unroll
    for (int r = 0; r < 4; ++r) {
      float c = x2[r] + y2 - 2.f*dot[r];
      cost[((size_t)bh*256 + j0 + r)*256 + tid] = sqrtf(fmaxf(c, 1e-12f));
    }
  } else {
    const int idx = blockIdx.x - 1024;
    const int l = idx & 63, bh = (idx >> 6) & 15, uv = idx >> 10;
    const float* S = uv ? Y : X;
    float* so = uv ? srtv : srtu;
    float* zo = uv ? lziv : lziu;
    float v = S[((size_t)bh*256 + tid)*64 + l];
#pragma unroll
    for (int k = 2; k <= 256; k <<= 1) {
#pragma unroll
      for (int j = k >> 1; j > 0; j >>= 1) {
        float o;
        if (j >= 64) {
          smem[tid] = v; __syncthreads();
          o = smem[tid ^ j]; __syncthreads();
        } else {
          o = __shfl_xor(v, j, 64);
        }
        const bool up    = ((tid & k) == 0);
        const bool lower = ((tid & j) == 0);
        float mn = fminf(v, o), mx = fmaxf(v, o);
        v = (up == lower) ? mn : mx;
      }
    }
    smem[tid] = v; __syncthreads();
    const int jc = 255 - tid;
    const float sv = smem[jc];
    const int lo = jc > 48 ? jc - 48 : 0;
    const int hi = jc < 207 ? jc + 48 : 255;
    float z = 0.f;
    for (int jj = lo; jj <= hi; ++jj) { float d = smem[jj] - sv; z += fexp2(d*d*CEXP); }
    const int base = (bh*64 + l)*256 + tid;
    so[base] = sv; zo[base] = -__log2f(z);
  }
}

// stage one 32-i slab of 128-row fp16 exp tables (swizzled, conflict-free).
// thread t: row r=t&127, octs gp,gp+1 (16 i's) of both EU and EV.
// e[8] chunks keep live-range small (register diet for 4 waves/SIMD).
__device__ __forceinline__ void stage_slab(int t, int ib, float uval, float vval,
                                           const float* __restrict__ srtU, const float* __restrict__ lziU,
                                           const float* __restrict__ srtV, const float* __restrict__ lziV,
                                           unsigned short* __restrict__ EU,
                                           unsigned short* __restrict__ EV) {
  const int r  = t & 127;
  const int gp = (t >> 7) << 1;
  const int i0 = ib + (gp << 3);
#pragma unroll
  for (int gg = 0; gg < 2; ++gg) {
    float e[8];
#pragma unroll
    for (int ii = 0; ii < 8; ++ii) {
      float d = uval - srtU[i0 + gg*8 + ii];
      e[ii] = fexp2(fmaf(d*d, CEXP, lziU[i0 + gg*8 + ii]));
    }
    uint4 w;
    w.x = __builtin_bit_cast(unsigned, __builtin_amdgcn_cvt_pkrtz(e[0], e[1]));
    w.y = __builtin_bit_cast(unsigned, __builtin_amdgcn_cvt_pkrtz(e[2], e[3]));
    w.z = __builtin_bit_cast(unsigned, __builtin_amdgcn_cvt_pkrtz(e[4], e[5]));
    w.w = __builtin_bit_cast(unsigned, __builtin_amdgcn_cvt_pkrtz(e[6], e[7]));
    *(uint4*)&EU[tswz(r, gp + gg)] = w;
  }
#pragma unroll
  for (int gg = 0; gg < 2; ++gg) {
    float e[8];
#pragma unroll
    for (int ii = 0; ii < 8; ++ii) {
      float d = vval - srtV[i0 + gg*8 + ii];
      e[ii] = fexp2(fmaf(d*d, CEXP, lziV[i0 + gg*8 + ii]));
    }
    uint4 w;
    w.x = __builtin_bit_cast(unsigned, __builtin_amdgcn_cvt_pkrtz(e[0], e[1]));
    w.y = __builtin_bit_cast(unsigned, __builtin_amdgcn_cvt_pkrtz(e[2], e[3]));
    w.z = __builtin_bit_cast(unsigned, __builtin_amdgcn_cvt_pkrtz(e[4], e[5]));
    w.w = __builtin_bit_cast(unsigned, __builtin_amdgcn_cvt_pkrtz(e[6], e[7]));
    *(uint4*)&EV[tswz(r, gp + gg)] = w;
  }
}

// Pass 1: per (tile, l, bh): 128x128 Gamma tile via pipelined fp16 MFMA
// (64x64 wave tiles, acc[16]); dot with cost -> parts; Gamma bf16 NT-store
// fragment-linear [group][l][lane].
__global__ __launch_bounds__(256, 4) void pass1_kernel(
    const float* __restrict__ X, const float* __restrict__ Y,
    const float* __restrict__ cost,
    const float* __restrict__ srtu, const float* __restrict__ lziu,
    const float* __restrict__ srtv, const float* __restrict__ lziv,
    float* __restrict__ parts, u32x2* __restrict__ gamma) {
  const int tile = blockIdx.x, l = blockIdx.y, bh = blockIdx.z;
  const int j0 = (tile >> 1) * 128, k0 = (tile & 1) * 128;
  const int tid = threadIdx.x, wave = tid >> 6, lane = tid & 63;
  const int wj = (wave & 1) * 64, wk = (wave >> 1) * 64;
  const int m = lane & 15, q = lane >> 4;
  const int inner = m*32 + (((q + (m >> 1)) & 3) << 3);

  __shared__ float srtU[256], lziU[256], srtV[256], lziV[256];
  __shared__ __align__(16) unsigned short EU0[128*32], EU1[128*32];
  __shared__ __align__(16) unsigned short EV0[128*32], EV1[128*32];
  __shared__ float red[4];
  // LDS: 4KB + 4x8KB = 36KB -> 4 blocks/CU

  const int lb = (bh*64 + l)*256;
  const int r  = tid & 127;
  const float uval = X[((size_t)bh*256 + j0 + r)*64 + l];
  const float vval = Y[((size_t)bh*256 + k0 + r)*64 + l];
  srtU[tid] = srtu[lb + tid]; lziU[tid] = lziu[lb + tid];
  srtV[tid] = srtv[lb + tid]; lziV[tid] = lziv[lb + tid];

  f32x4 acc[16];
#pragma unroll
  for (int t = 0; t < 16; ++t) acc[t] = (f32x4){0.f, 0.f, 0.f, 0.f};

  __syncthreads();
  stage_slab(tid, 0, uval, vval, srtU, lziU, srtV, lziV, EU0, EV0);
  __syncthreads();
#pragma unroll 1
  for (int s = 0; s < 8; ++s) {
    const unsigned short* EUc = (s & 1) ? EU1 : EU0;
    const unsigned short* EVc = (s & 1) ? EV1 : EV0;
    unsigned short* EUn = (s & 1) ? EU0 : EU1;
    unsigned short* EVn = (s & 1) ? EV0 : EV1;
    half8 A[4], B[4];
#pragma unroll
    for (int mt = 0; mt < 4; ++mt) A[mt] = ldsh8(&EUc[(wj + mt*16)*32 + inner]);
#pragma unroll
    for (int nt = 0; nt < 4; ++nt) B[nt] = ldsh8(&EVc[(wk + nt*16)*32 + inner]);
    if (s < 7)
      stage_slab(tid, (s+1)*32, uval, vval, srtU, lziU, srtV, lziV, EUn, EVn);
#pragma unroll
    for (int mt = 0; mt < 4; ++mt)
#pragma unroll
      for (int nt = 0; nt < 4; ++nt)
        acc[mt*4+nt] = __builtin_amdgcn_mfma_f32_16x16x32_f16(A[mt], B[nt], acc[mt*4+nt], 0, 0, 0);
    __syncthreads();
  }

  // epilogue: dot with cost + coalesced NT bf16 Gamma store.
  // C/D map: col=lane&15, row=(lane>>4)*4+reg
  const float* cb = cost + (size_t)bh * 65536;
  const int gbase = ((bh*4 + tile)*4 + wave) * 16;
  float part = 0.f;
#pragma unroll
  for (int mt = 0; mt < 4; ++mt) {
#pragma unroll
    for (int nt = 0; nt < 4; ++nt) {
      const int col  = k0 + wk + nt*16 + m;
      const int rowb = j0 + wj + mt*16 + q*4;
      f32x4 a = acc[mt*4 + nt];
      part += a.x*cb[(size_t)(rowb+0)*256 + col] + a.y*cb[(size_t)(rowb+1)*256 + col]
            + a.z*cb[(size_t)(rowb+2)*256 + col] + a.w*cb[(size_t)(rowb+3)*256 + col];
      u32x2 pk;
      pk.x = bf16r(a.x) | (bf16r(a.y) << 16);
      pk.y = bf16r(a.z) | (bf16r(a.w) << 16);
      __builtin_nontemporal_store(pk, &gamma[((size_t)(gbase + mt*4 + nt)*64 + l)*64 + lane]);
    }
  }
#pragma unroll
  for (int o = 32; o > 0; o >>= 1) part += __shfl_down(part, o, 64);
  if (lane == 0) red[wave] = part;
  __syncthreads();
  if (tid == 0) parts[(size_t)tile*1024 + bh*64 + l] = red[0] + red[1] + red[2] + red[3];
}

// wsum: per block, recompute softmax weights from the 4 swds partials, then
// out = sum_l w_l * Gamma_l (each wave NT-streams one 32KB fragment-linear chunk).
__global__ __launch_bounds__(256) void wsum_kernel(const u32x2* __restrict__ g,
                                                   const float* __restrict__ parts,
                                                   float* __restrict__ out) {
  const int wv = threadIdx.x >> 6, lane = threadIdx.x & 63;
  const int bh = blockIdx.x >> 6;                 // 64 blocks per bh
  __shared__ float w[64];
  if (wv == 0) {
    float s = parts[bh*64 + lane] + parts[1024 + bh*64 + lane]
            + parts[2048 + bh*64 + lane] + parts[3072 + bh*64 + lane];
    float v = -TEMP * s * 1.4426950408889634f;    // log2-domain logits
    float mx = v;
#pragma unroll
    for (int o = 32; o > 0; o >>= 1) mx = fmaxf(mx, __shfl_xor(mx, o, 64));
    float e = fexp2(v - mx);
    float ssum = e;
#pragma unroll
    for (int o = 32; o > 0; o >>= 1) ssum += __shfl_xor(ssum, o, 64);
    w[lane] = e / ssum;
  }
  __syncthreads();
  const int group = blockIdx.x * 4 + wv;
  const u32x2* gp = g + (size_t)group*4096 + lane;
  float4 acc = {0.f, 0.f, 0.f, 0.f};
#pragma unroll 8
  for (int l = 0; l < 64; ++l) {
    u32x2 pk = __builtin_nontemporal_load(gp + l*64);
    float wl = w[l];
    acc.x += wl * __uint_as_float(pk.x << 16);
    acc.y += wl * __uint_as_float(pk.x & 0xFFFF0000u);
    acc.z += wl * __uint_as_float(pk.y << 16);
    acc.w += wl * __uint_as_float(pk.y & 0xFFFF0000u);
  }
  const int frag = group & 15;
  const int idx  = group >> 4;                    // (bh*4+tile)*4+wave
  const int wave = idx & 3, tile = (idx >> 2) & 3;
  const int mt = frag >> 2, nt = frag & 3;
  const int m = lane & 15, q = lane >> 4;
  const int row = (tile >> 1)*128 + (wave & 1)*64 + mt*16 + q*4;
  const int col = (tile & 1)*128 + (wave >> 1)*64 + nt*16 + m;
  float* ob = out + ((size_t)bh*256 + row)*256 + col;
  __builtin_nontemporal_store(acc.x, &ob[0]);
  __builtin_nontemporal_store(acc.y, &ob[256]);
  __builtin_nontemporal_store(acc.z, &ob[512]);
  __builtin_nontemporal_store(acc.w, &ob[768]);
}

extern "C" void kernel_launch(void* const* d_in, const int* in_sizes, int n_in,
                              void* d_out, int out_size, void* d_ws, size_t ws_size,
                              hipStream_t stream) {
  (void)in_sizes; (void)n_in; (void)out_size; (void)ws_size;
  const float* X = (const float*)d_in[0];
  const float* Y = (const float*)d_in[1];
  float* out = (float*)d_out;
  float* ws  = (float*)d_ws;
  float* cost  = ws;                    // 1048576
  float* srtu  = ws   + 1048576;
  float* lziu  = srtu + 262144;
  float* srtv  = lziu + 262144;
  float* lziv  = srtv + 262144;
  float* parts = lziv + 262144;         // 4096 (written, not accumulated: no memset)
  u32x2* gamma = (u32x2*)(parts + 4096);// 4096 groups x 64 l x 64 lanes x 8B = 134MB

  prep_kernel <<<dim3(3072),      256, 0, stream>>>(X, Y, cost, srtu, lziu, srtv, lziv);
  pass1_kernel<<<dim3(4, 64, 16), 256, 0, stream>>>(X, Y, cost, srtu, lziu, srtv, lziv,
                                                    parts, gamma);
  wsum_kernel <<<dim3(1024),      256, 0, stream>>>(gamma, parts, out);
}

// Round 10
// 162.844 us; speedup vs baseline: 1.7575x; 1.0408x over previous
//
#include <hip/hip_runtime.h>
#include <math.h>

#define INV_TAU 1000.0f
#define TEMP    0.1f
#define CEXP    -1442.6950408889634f   // -1000 * log2(e)
#define SQRTC   37.98283767f           // sqrt(1000 * log2(e))

// Problem: B=2,H=8 -> BH=16; N=256; L=64.  X,Y: [BH,256,64] f32. out: [BH,256,256] f32.
//
// Round 10: strip blocks (128j x 256k, 512 thr, 8 waves, acc[16]/wave) cut
// staging redundancy 2x -> 1.5x; 3-op exp entries (prep pre-scales sort values:
// nss=-sqrt(c)*s, entry = add + fma(-d,d,lz) + exp2). pass1 was 95% issue-
// saturated (77 VALU + 18 MFMA) -> only instruction removal helps.
//
// ws (floats): cost[1048576] | nssu|lziu|nssv|lziv (262144 ea) |
//              parts[2048] | gamma u32x2[4096*64*64] (134MB)

typedef __attribute__((ext_vector_type(8))) _Float16 half8;
typedef __attribute__((ext_vector_type(8))) short short8;
typedef __attribute__((ext_vector_type(4))) float f32x4;
typedef __attribute__((ext_vector_type(2))) unsigned int u32x2;

__device__ __forceinline__ float fexp2(float x) { return __builtin_amdgcn_exp2f(x); }

__device__ __forceinline__ half8 ldsh8(const unsigned short* p) {
  return __builtin_bit_cast(half8, *(const short8*)p);
}

__device__ __forceinline__ unsigned bf16r(float f) {   // bf16 RNE, low 16 bits
  unsigned u = __float_as_uint(f);
  return (u + 0x7FFFu + ((u >> 16) & 1u)) >> 16;
}

// swizzled short-offset of (row, oct g) in a 32-short-per-row table
__device__ __forceinline__ int tswz(int row, int g) {
  return row * 32 + (((g + (row >> 1)) & 3) << 3);
}

// prep: blockIdx.x < 1024 -> cost quad-row tile; else sortz for (l, bh, X/Y).
// sortz stores nss = -SQRTC*sorted_val and lz = -log2(Z) (banded Z, tail<e^-60).
__global__ __launch_bounds__(256) void prep_kernel(const float* __restrict__ X,
                                                   const float* __restrict__ Y,
                                                   float* __restrict__ cost,
                                                   float* __restrict__ nssu, float* __restrict__ lziu,
                                                   float* __restrict__ nssv, float* __restrict__ lziv) {
  __shared__ __align__(16) float smem[256];
  const int tid = threadIdx.x;
  if (blockIdx.x < 1024) {
    const int jq = blockIdx.x & 63, bh = blockIdx.x >> 6;
    const int j0 = jq * 4;
    smem[tid] = X[((size_t)bh*256 + j0 + (tid >> 6))*64 + (tid & 63)];
    __syncthreads();
    const float4* yp = (const float4*)(Y + ((size_t)bh*256 + tid)*64);
    float dot[4] = {0.f,0.f,0.f,0.f}, x2[4] = {0.f,0.f,0.f,0.f}, y2 = 0.f;
#pragma unroll
    for (int t = 0; t < 16; ++t) {
      float4 yv = yp[t];
      y2 += yv.x*yv.x + yv.y*yv.y + yv.z*yv.z + yv.w*yv.w;
#pragma unroll
      for (int r = 0; r < 4; ++r) {
        float4 xv = ((const float4*)(smem + r*64))[t];
        dot[r] += xv.x*yv.x + xv.y*yv.y + xv.z*yv.z + xv.w*yv.w;
        x2[r]  += xv.x*xv.x + xv.y*xv.y + xv.z*xv.z + xv.w*xv.w;
      }
    }
#pragma unroll
    for (int r = 0; r < 4; ++r) {
      float c = x2[r] + y2 - 2.f*dot[r];
      cost[((size_t)bh*256 + j0 + r)*256 + tid] = sqrtf(fmaxf(c, 1e-12f));
    }
  } else {
    const int idx = blockIdx.x - 1024;
    const int l = idx & 63, bh = (idx >> 6) & 15, uv = idx >> 10;
    const float* S = uv ? Y : X;
    float* so = uv ? nssv : nssu;
    float* zo = uv ? lziv : lziu;
    float v = S[((size_t)bh*256 + tid)*64 + l];
#pragma unroll
    for (int k = 2; k <= 256; k <<= 1) {
#pragma unroll
      for (int j = k >> 1; j > 0; j >>= 1) {
        float o;
        if (j >= 64) {
          smem[tid] = v; __syncthreads();
          o = smem[tid ^ j]; __syncthreads();
        } else {
          o = __shfl_xor(v, j, 64);
        }
        const bool up    = ((tid & k) == 0);
        const bool lower = ((tid & j) == 0);
        float mn = fminf(v, o), mx = fmaxf(v, o);
        v = (up == lower) ? mn : mx;
      }
    }
    smem[tid] = v; __syncthreads();
    const int jc = 255 - tid;
    const float sv = smem[jc];
    const int lo = jc > 48 ? jc - 48 : 0;
    const int hi = jc < 207 ? jc + 48 : 255;
    float z = 0.f;
    for (int jj = lo; jj <= hi; ++jj) { float d = smem[jj] - sv; z += fexp2(d*d*CEXP); }
    const int base = (bh*64 + l)*256 + tid;
    so[base] = -SQRTC * sv; zo[base] = -__log2f(z);
  }
}

// stage one 32-i slab (512 threads): EU (128 rows): thread t -> row t&127,
// oct t>>7 (8 entries). EV (256 rows): row t&255, octs (t>>8)*2+{0,1} (16).
// Entry: d = usc + nss_i; e = exp2(fma(-d,d,lz_i)).  3 VALU ops/entry.
__device__ __forceinline__ void stage_slab(int t, int ib, float usc, float vsc,
                                           const float* __restrict__ nssU, const float* __restrict__ lzU,
                                           const float* __restrict__ nssV, const float* __restrict__ lzV,
                                           unsigned short* __restrict__ EU,
                                           unsigned short* __restrict__ EV) {
  {
    const int r = t & 127, g = t >> 7;
    const int i0 = ib + (g << 3);
    float e[8];
#pragma unroll
    for (int ii = 0; ii < 8; ++ii) {
      float d = usc + nssU[i0 + ii];
      e[ii] = fexp2(fmaf(-d, d, lzU[i0 + ii]));
    }
    uint4 w;
    w.x = __builtin_bit_cast(unsigned, __builtin_amdgcn_cvt_pkrtz(e[0], e[1]));
    w.y = __builtin_bit_cast(unsigned, __builtin_amdgcn_cvt_pkrtz(e[2], e[3]));
    w.z = __builtin_bit_cast(unsigned, __builtin_amdgcn_cvt_pkrtz(e[4], e[5]));
    w.w = __builtin_bit_cast(unsigned, __builtin_amdgcn_cvt_pkrtz(e[6], e[7]));
    *(uint4*)&EU[tswz(r, g)] = w;
  }
  {
    const int r = t & 255;
    const int gp = (t >> 8) << 1;
#pragma unroll
    for (int gg = 0; gg < 2; ++gg) {
      const int i0 = ib + ((gp + gg) << 3);
      float e[8];
#pragma unroll
      for (int ii = 0; ii < 8; ++ii) {
        float d = vsc + nssV[i0 + ii];
        e[ii] = fexp2(fmaf(-d, d, lzV[i0 + ii]));
      }
      uint4 w;
      w.x = __builtin_bit_cast(unsigned, __builtin_amdgcn_cvt_pkrtz(e[0], e[1]));
      w.y = __builtin_bit_cast(unsigned, __builtin_amdgcn_cvt_pkrtz(e[2], e[3]));
      w.z = __builtin_bit_cast(unsigned, __builtin_amdgcn_cvt_pkrtz(e[4], e[5]));
      w.w = __builtin_bit_cast(unsigned, __builtin_amdgcn_cvt_pkrtz(e[6], e[7]));
      *(uint4*)&EV[tswz(r, gp + gg)] = w;
    }
  }
}

// Pass 1: per (strip sb, l, bh): 128j x 256k Gamma strip via pipelined fp16
// MFMA (8 waves, 64x64 wave tiles, acc[16]); dot with cost -> parts; Gamma
// bf16 NT-store fragment-linear [group][l][lane].
__global__ __launch_bounds__(512, 4) void pass1_kernel(
    const float* __restrict__ X, const float* __restrict__ Y,
    const float* __restrict__ cost,
    const float* __restrict__ nssu, const float* __restrict__ lziu,
    const float* __restrict__ nssv, const float* __restrict__ lziv,
    float* __restrict__ parts, u32x2* __restrict__ gamma) {
  const int sb = blockIdx.x, l = blockIdx.y, bh = blockIdx.z;
  const int j0 = sb * 128;
  const int tid = threadIdx.x, wave = tid >> 6, lane = tid & 63;
  const int wj = (wave & 1) * 64, wk = (wave >> 1) * 64;
  const int m = lane & 15, q = lane >> 4;
  const int inner = m*32 + (((q + (m >> 1)) & 3) << 3);

  __shared__ float nssU[256], lzU[256], nssV[256], lzV[256];
  __shared__ __align__(16) unsigned short EU0[128*32], EU1[128*32];
  __shared__ __align__(16) unsigned short EV0[256*32], EV1[256*32];
  __shared__ float red[8];
  // LDS: 4KB + 16KB + 32KB = 52.2KB -> 2 blocks/CU x 8 waves = 4 waves/SIMD

  const int lb = (bh*64 + l)*256;
  const float usc = SQRTC * X[((size_t)bh*256 + j0 + (tid & 127))*64 + l];
  const float vsc = SQRTC * Y[((size_t)bh*256 + (tid & 255))*64 + l];
  if (tid < 256) { nssU[tid] = nssu[lb + tid]; lzU[tid] = lziu[lb + tid]; }
  else { const int t2 = tid - 256; nssV[t2] = nssv[lb + t2]; lzV[t2] = lziv[lb + t2]; }

  f32x4 acc[16];
#pragma unroll
  for (int t = 0; t < 16; ++t) acc[t] = (f32x4){0.f, 0.f, 0.f, 0.f};

  __syncthreads();
  stage_slab(tid, 0, usc, vsc, nssU, lzU, nssV, lzV, EU0, EV0);
  __syncthreads();
#pragma unroll 1
  for (int s = 0; s < 8; ++s) {
    const unsigned short* EUc = (s & 1) ? EU1 : EU0;
    const unsigned short* EVc = (s & 1) ? EV1 : EV0;
    unsigned short* EUn = (s & 1) ? EU0 : EU1;
    unsigned short* EVn = (s & 1) ? EV0 : EV1;
    half8 A[4], B[4];
#pragma unroll
    for (int mt = 0; mt < 4; ++mt) A[mt] = ldsh8(&EUc[(wj + mt*16)*32 + inner]);
#pragma unroll
    for (int nt = 0; nt < 4; ++nt) B[nt] = ldsh8(&EVc[(wk + nt*16)*32 + inner]);
    if (s < 7)
      stage_slab(tid, (s+1)*32, usc, vsc, nssU, lzU, nssV, lzV, EUn, EVn);
#pragma unroll
    for (int mt = 0; mt < 4; ++mt)
#pragma unroll
      for (int nt = 0; nt < 4; ++nt)
        acc[mt*4+nt] = __builtin_amdgcn_mfma_f32_16x16x32_f16(A[mt], B[nt], acc[mt*4+nt], 0, 0, 0);
    __syncthreads();
  }

  // epilogue: dot with cost + coalesced NT bf16 Gamma store.
  // C/D map: col=lane&15, row=(lane>>4)*4+reg
  const float* cb = cost + (size_t)bh * 65536;
  const int gbase = ((bh*2 + sb)*8 + wave) * 16;
  float part = 0.f;
#pragma unroll
  for (int mt = 0; mt < 4; ++mt) {
#pragma unroll
    for (int nt = 0; nt < 4; ++nt) {
      const int col  = wk + nt*16 + m;
      const int rowb = j0 + wj + mt*16 + q*4;
      f32x4 a = acc[mt*4 + nt];
      part += a.x*cb[(size_t)(rowb+0)*256 + col] + a.y*cb[(size_t)(rowb+1)*256 + col]
            + a.z*cb[(size_t)(rowb+2)*256 + col] + a.w*cb[(size_t)(rowb+3)*256 + col];
      u32x2 pk;
      pk.x = bf16r(a.x) | (bf16r(a.y) << 16);
      pk.y = bf16r(a.z) | (bf16r(a.w) << 16);
      __builtin_nontemporal_store(pk, &gamma[((size_t)(gbase + mt*4 + nt)*64 + l)*64 + lane]);
    }
  }
#pragma unroll
  for (int o = 32; o > 0; o >>= 1) part += __shfl_down(part, o, 64);
  if (lane == 0) red[wave] = part;
  __syncthreads();
  if (tid == 0) {
    float s8 = red[0]+red[1]+red[2]+red[3]+red[4]+red[5]+red[6]+red[7];
    parts[sb*1024 + bh*64 + l] = s8;
  }
}

// wsum: per block, recompute softmax weights from the 2 swds partials, then
// out = sum_l w_l * Gamma_l (each wave NT-streams one 32KB fragment-linear chunk).
__global__ __launch_bounds__(256) void wsum_kernel(const u32x2* __restrict__ g,
                                                   const float* __restrict__ parts,
                                                   float* __restrict__ out) {
  const int wv = threadIdx.x >> 6, lane = threadIdx.x & 63;
  const int bh = blockIdx.x >> 6;                 // 64 blocks per bh (uniform)
  __shared__ float w[64];
  if (wv == 0) {
    float s = parts[bh*64 + lane] + parts[1024 + bh*64 + lane];
    float v = -TEMP * s * 1.4426950408889634f;    // log2-domain logits
    float mx = v;
#pragma unroll
    for (int o = 32; o > 0; o >>= 1) mx = fmaxf(mx, __shfl_xor(mx, o, 64));
    float e = fexp2(v - mx);
    float ssum = e;
#pragma unroll
    for (int o = 32; o > 0; o >>= 1) ssum += __shfl_xor(ssum, o, 64);
    w[lane] = e / ssum;
  }
  __syncthreads();
  const int group = blockIdx.x * 4 + wv;
  const u32x2* gp = g + (size_t)group*4096 + lane;
  float4 acc = {0.f, 0.f, 0.f, 0.f};
#pragma unroll 8
  for (int l = 0; l < 64; ++l) {
    u32x2 pk = __builtin_nontemporal_load(gp + l*64);
    float wl = w[l];
    acc.x += wl * __uint_as_float(pk.x << 16);
    acc.y += wl * __uint_as_float(pk.x & 0xFFFF0000u);
    acc.z += wl * __uint_as_float(pk.y << 16);
    acc.w += wl * __uint_as_float(pk.y & 0xFFFF0000u);
  }
  const int frag = group & 15;
  const int idx  = group >> 4;                    // (bh*2+sb)*8 + wave
  const int wave = idx & 7, sbb = (idx >> 3) & 1;
  const int mt = frag >> 2, nt = frag & 3;
  const int m = lane & 15, q = lane >> 4;
  const int row = sbb*128 + (wave & 1)*64 + mt*16 + q*4;
  const int col = (wave >> 1)*64 + nt*16 + m;
  float* ob = out + ((size_t)bh*256 + row)*256 + col;
  __builtin_nontemporal_store(acc.x, &ob[0]);
  __builtin_nontemporal_store(acc.y, &ob[256]);
  __builtin_nontemporal_store(acc.z, &ob[512]);
  __builtin_nontemporal_store(acc.w, &ob[768]);
}

extern "C" void kernel_launch(void* const* d_in, const int* in_sizes, int n_in,
                              void* d_out, int out_size, void* d_ws, size_t ws_size,
                              hipStream_t stream) {
  (void)in_sizes; (void)n_in; (void)out_size; (void)ws_size;
  const float* X = (const float*)d_in[0];
  const float* Y = (const float*)d_in[1];
  float* out = (float*)d_out;
  float* ws  = (float*)d_ws;
  float* cost  = ws;                    // 1048576
  float* nssu  = ws   + 1048576;
  float* lziu  = nssu + 262144;
  float* nssv  = lziu + 262144;
  float* lziv  = nssv + 262144;
  float* parts = lziv + 262144;         // 2048 (written, not accumulated)
  u32x2* gamma = (u32x2*)(parts + 2048);// 4096 groups x 64 l x 64 lanes x 8B = 134MB

  prep_kernel <<<dim3(3072),      256, 0, stream>>>(X, Y, cost, nssu, lziu, nssv, lziv);
  pass1_kernel<<<dim3(2, 64, 16), 512, 0, stream>>>(X, Y, cost, nssu, lziu, nssv, lziv,
                                                    parts, gamma);
  wsum_kernel <<<dim3(1024),      256, 0, stream>>>(gamma, parts, out);
}